// Round 1
// baseline (6930.196 us; speedup 1.0000x reference)
//
#include <hip/hip_runtime.h>
#include <cstddef>
#include <cstdint>

// DynamicAutoencoder on MI355X — Round 1: correct fp32 baseline.
// Pipeline:
//   x0 = window[:,0,:]; z0 = enc(x0); x0r = dec(z0)
//   p  = koopman_mlp(z0); z_pred[b,t] = (e^{(mu+i*omega)dt})^{t+1} z0   (closed form)
//   per 8128-row chunk: z_true = enc(targets), x_pred = dec(z_pred), fused losses
// Losses accumulate into double atomics; finalize writes 4 f32 outputs.

#define KDT 0.01f

// ---------------------------------------------------------------------------
// GEMM: C = act(A @ W + bias).  A: MxK row-major f32, W: KxN row-major f32.
// 64x64 tile, BK=16, 256 threads, 4x4 micro-tile. M%64==0, N%64==0, K%16==0.
// ---------------------------------------------------------------------------
template <bool TANH>
__global__ __launch_bounds__(256) void k_gemm_bias(const float* __restrict__ A,
                                                   const float* __restrict__ W,
                                                   const float* __restrict__ bias,
                                                   float* __restrict__ C,
                                                   int M, int N, int K)
{
    __shared__ __align__(16) float As[16][68];   // transposed A tile: As[k][row]
    __shared__ __align__(16) float Bs[16][68];   // Bs[k][col]

    const int t  = threadIdx.x;
    const int bm = blockIdx.y;
    const int bn = blockIdx.x;
    const int tr = t >> 4;       // 0..15 row group
    const int tc = t & 15;       // 0..15 col group
    const int lar = t >> 2;      // 0..63 A-tile row to load
    const int lac = t & 3;       // 0..3  A-tile float4 column
    const int lbr = t >> 4;      // 0..15 W-tile k row
    const int lbc = t & 15;      // 0..15 W-tile float4 column

    const float* Ab = A + (size_t)bm * 64 * K;
    const float* Wb = W + (size_t)bn * 64;

    float acc[4][4] = {};

    for (int k0 = 0; k0 < K; k0 += 16) {
        const float4 av = *reinterpret_cast<const float4*>(Ab + (size_t)lar * K + (k0 + lac * 4));
        const float4 bv = *reinterpret_cast<const float4*>(Wb + (size_t)(k0 + lbr) * N + lbc * 4);
        As[lac * 4 + 0][lar] = av.x;
        As[lac * 4 + 1][lar] = av.y;
        As[lac * 4 + 2][lar] = av.z;
        As[lac * 4 + 3][lar] = av.w;
        *reinterpret_cast<float4*>(&Bs[lbr][lbc * 4]) = bv;
        __syncthreads();
#pragma unroll
        for (int kk = 0; kk < 16; ++kk) {
            const float4 a4 = *reinterpret_cast<const float4*>(&As[kk][tr * 4]);
            const float4 b4 = *reinterpret_cast<const float4*>(&Bs[kk][tc * 4]);
            const float ar[4] = {a4.x, a4.y, a4.z, a4.w};
            const float br[4] = {b4.x, b4.y, b4.z, b4.w};
#pragma unroll
            for (int i = 0; i < 4; ++i)
#pragma unroll
                for (int j = 0; j < 4; ++j)
                    acc[i][j] = fmaf(ar[i], br[j], acc[i][j]);
        }
        __syncthreads();
    }

    const float4 bb = *reinterpret_cast<const float4*>(bias + bn * 64 + tc * 4);
    const float bbr[4] = {bb.x, bb.y, bb.z, bb.w};
#pragma unroll
    for (int i = 0; i < 4; ++i) {
        float o[4];
#pragma unroll
        for (int j = 0; j < 4; ++j) {
            float v = acc[i][j] + bbr[j];
            o[j] = TANH ? tanhf(v) : v;
        }
        *reinterpret_cast<float4*>(C + (size_t)(bm * 64 + tr * 4 + i) * N + bn * 64 + tc * 4) =
            make_float4(o[0], o[1], o[2], o[3]);
    }
}

// ---------------------------------------------------------------------------
// Gathers (window is (512, 128, 512) f32)
// ---------------------------------------------------------------------------
__global__ __launch_bounds__(256) void k_gather_x0(const float* __restrict__ win,
                                                   float* __restrict__ out)
{
    int i = blockIdx.x * 256 + threadIdx.x;   // over 512*128 float4s
    if (i >= 512 * 128) return;
    int b = i >> 7, c = i & 127;
    const float4 v = *reinterpret_cast<const float4*>(win + (size_t)b * (128 * 512) + c * 4);
    *reinterpret_cast<float4*>(out + (size_t)b * 512 + c * 4) = v;
}

__global__ __launch_bounds__(256) void k_gather_tgt(const float* __restrict__ win,
                                                    float* __restrict__ out, int row0)
{
    int i = blockIdx.x * 256 + threadIdx.x;   // over 8128*128 float4s
    if (i >= 8128 * 128) return;
    int r = i >> 7, c = i & 127;
    int g = row0 + r;
    int b = g / 127;
    int t = g - b * 127 + 1;                  // targets are window[:,1:,:]
    const float4 v = *reinterpret_cast<const float4*>(win + ((size_t)(b * 128 + t)) * 512 + c * 4);
    *reinterpret_cast<float4*>(out + (size_t)r * 512 + c * 4) = v;
}

// ---------------------------------------------------------------------------
// Koopman rollout, closed form.  pK: (512,128)  z0: (512,128)  zp: (65024,128)
// pair n: mu=pK[b][2n], om=pK[b][2n+1]; z_t = e^{mu*dt*t} R(om*dt*t) z0-pair
// ---------------------------------------------------------------------------
__global__ __launch_bounds__(256) void k_koopman(const float* __restrict__ pK,
                                                 const float* __restrict__ z0,
                                                 float* __restrict__ zp)
{
    int idx = blockIdx.x * 256 + threadIdx.x;   // over 512*127*64 pairs
    if (idx >= 512 * 127 * 64) return;
    int n = idx & 63;
    int j = (idx >> 6) % 127;
    int b = idx / (64 * 127);
    const float2 z = *reinterpret_cast<const float2*>(z0 + (size_t)b * 128 + 2 * n);
    const float2 q = *reinterpret_cast<const float2*>(pK + (size_t)b * 128 + 2 * n);
    const float tf = KDT * (float)(j + 1);
    const float e = expf(q.x * tf);
    const float c = cosf(q.y * tf);
    const float s = sinf(q.y * tf);
    const size_t row = (size_t)b * 127 + j;
    *reinterpret_cast<float2*>(zp + row * 128 + 2 * n) =
        make_float2(e * (c * z.x - s * z.y), e * (s * z.x + c * z.y));
}

// ---------------------------------------------------------------------------
// Sum of squared differences -> double atomic accumulator. n4 = n/4.
// ---------------------------------------------------------------------------
__global__ __launch_bounds__(256) void k_sqdiff(const float* __restrict__ a,
                                                const float* __restrict__ b,
                                                int n4, double* __restrict__ acc)
{
    double s = 0.0;
    for (int i = blockIdx.x * 256 + threadIdx.x; i < n4; i += gridDim.x * 256) {
        const float4 x = reinterpret_cast<const float4*>(a)[i];
        const float4 y = reinterpret_cast<const float4*>(b)[i];
        const float dx = x.x - y.x, dy = x.y - y.y, dz = x.z - y.z, dw = x.w - y.w;
        s += (double)(dx * dx) + (double)(dy * dy) + (double)(dz * dz) + (double)(dw * dw);
    }
    __shared__ double sm[256];
    sm[threadIdx.x] = s;
    __syncthreads();
    for (int o = 128; o > 0; o >>= 1) {
        if (threadIdx.x < o) sm[threadIdx.x] += sm[threadIdx.x + o];
        __syncthreads();
    }
    if (threadIdx.x == 0) atomicAdd(acc, sm[0]);
}

__global__ void k_finalize(const double* __restrict__ acc, float* __restrict__ out)
{
    if (threadIdx.x == 0 && blockIdx.x == 0) {
        const double recon  = acc[0] / (512.0 * 512.0);
        const double linear = acc[1] / (65024.0 * 128.0);
        const double pred   = acc[2] / (65024.0 * 512.0);
        out[0] = (float)(recon + linear + pred);
        out[1] = (float)recon;
        out[2] = (float)linear;
        out[3] = (float)pred;
    }
}

// ---------------------------------------------------------------------------
extern "C" void kernel_launch(void* const* d_in, const int* in_sizes, int n_in,
                              void* d_out, int out_size, void* d_ws, size_t ws_size,
                              hipStream_t stream)
{
    const float* window = (const float*)d_in[0];
    const float* eW1 = (const float*)d_in[1];
    const float* eb1 = (const float*)d_in[2];
    const float* eW2 = (const float*)d_in[3];
    const float* eb2 = (const float*)d_in[4];
    const float* eW3 = (const float*)d_in[5];
    const float* eb3 = (const float*)d_in[6];
    const float* dW1 = (const float*)d_in[7];
    const float* db1 = (const float*)d_in[8];
    const float* dW2 = (const float*)d_in[9];
    const float* db2 = (const float*)d_in[10];
    const float* dW3 = (const float*)d_in[11];
    const float* db3 = (const float*)d_in[12];
    const float* kW1 = (const float*)d_in[13];
    const float* kb1 = (const float*)d_in[14];
    const float* kW2 = (const float*)d_in[15];
    const float* kb2 = (const float*)d_in[16];
    float* out = (float*)d_out;

    char* p = (char*)d_ws;
    size_t off = 256;                         // [0,32) = 3 double accumulators
    double* acc = (double*)p;
    auto take = [&](size_t elems) -> float* {
        float* r = (float*)(p + off);
        off += ((elems * 4 + 255) / 256) * 256;
        return r;
    };
    float* x0buf = take(512 * 512);
    float* hA    = take(512 * 1024);
    float* hB    = take(512 * 1024);
    float* z0    = take(512 * 128);
    float* x0r   = take(512 * 512);
    float* hK    = take(512 * 128);
    float* pK    = take(512 * 128);
    float* zpred = take((size_t)65024 * 128);
    float* cIn   = take((size_t)8128 * 512);
    float* cH1   = take((size_t)8128 * 1024);
    float* cH2   = take((size_t)8128 * 1024);
    float* cZ    = take((size_t)8128 * 128);
    float* cX    = take((size_t)8128 * 512);
    (void)ws_size; (void)in_sizes; (void)n_in; (void)out_size;

    hipMemsetAsync(acc, 0, 32, stream);

    auto G = [&](const float* A, const float* W, const float* b, float* C,
                 int M, int N, int K, bool do_tanh) {
        dim3 grid(N / 64, M / 64);
        if (do_tanh) k_gemm_bias<true><<<grid, 256, 0, stream>>>(A, W, b, C, M, N, K);
        else         k_gemm_bias<false><<<grid, 256, 0, stream>>>(A, W, b, C, M, N, K);
    };

    // x0 path
    k_gather_x0<<<(512 * 128 + 255) / 256, 256, 0, stream>>>(window, x0buf);
    G(x0buf, eW1, eb1, hA, 512, 1024, 512, true);
    G(hA,    eW2, eb2, hB, 512, 1024, 1024, true);
    G(hB,    eW3, eb3, z0, 512, 128, 1024, false);
    G(z0,    dW1, db1, hA, 512, 1024, 128, true);
    G(hA,    dW2, db2, hB, 512, 1024, 1024, true);
    G(hB,    dW3, db3, x0r, 512, 512, 1024, false);
    k_sqdiff<<<256, 256, 0, stream>>>(x0r, x0buf, 512 * 512 / 4, acc + 0);

    // koopman params + rollout
    G(z0, kW1, kb1, hK, 512, 128, 128, true);
    G(hK, kW2, kb2, pK, 512, 128, 128, false);
    k_koopman<<<(512 * 127 * 64 + 255) / 256, 256, 0, stream>>>(pK, z0, zpred);

    // big stacks, 8 chunks of 8128 rows
    for (int c = 0; c < 8; ++c) {
        float* zpc = zpred + (size_t)c * 8128 * 128;
        k_gather_tgt<<<(8128 * 128 + 255) / 256, 256, 0, stream>>>(window, cIn, c * 8128);
        G(cIn, eW1, eb1, cH1, 8128, 1024, 512, true);
        G(cH1, eW2, eb2, cH2, 8128, 1024, 1024, true);
        G(cH2, eW3, eb3, cZ, 8128, 128, 1024, false);
        k_sqdiff<<<512, 256, 0, stream>>>(zpc, cZ, 8128 * 128 / 4, acc + 1);
        G(zpc, dW1, db1, cH1, 8128, 1024, 128, true);
        G(cH1, dW2, db2, cH2, 8128, 1024, 1024, true);
        G(cH2, dW3, db3, cX, 8128, 512, 1024, false);
        k_sqdiff<<<512, 256, 0, stream>>>(cX, cIn, 8128 * 512 / 4, acc + 2);
    }

    k_finalize<<<1, 64, 0, stream>>>(acc, out);
}

// Round 2
// 1989.257 us; speedup vs baseline: 3.4838x; 3.4838x over previous
//
#include <hip/hip_runtime.h>
#include <cstddef>
#include <cstdint>

// DynamicAutoencoder — Round 2: f16 MFMA GEMMs (m97 structure), fp32 elsewhere.
//   - weights transposed+converted to f16 [N][K] once per launch
//   - 128x128 tile, BK=32, 4 waves, 4x4 16x16x32 f16 MFMA fragments, fp32 acc
//   - global_load_lds width=16 staging (linear LDS)
//   - koopman closed-form, recomputed in loss kernel (no big zpred buffer)
//   - losses in double atomics

#define KDT 0.01f
#define M_CH 16256          // 127 tiles of 128 rows; 4 chunks cover 65024

typedef _Float16 f16;
typedef f16 f16x8 __attribute__((ext_vector_type(8)));
typedef float f32x4 __attribute__((ext_vector_type(4)));

typedef __attribute__((address_space(1))) const unsigned int gu32;
typedef __attribute__((address_space(3))) unsigned int lu32;

__device__ __forceinline__ void gl_lds16(const void* g, void* l) {
    __builtin_amdgcn_global_load_lds((gu32*)g, (lu32*)l, 16, 0, 0);
}

__device__ __forceinline__ float fast_tanh(float x) {
    x = fminf(fmaxf(x, -15.f), 15.f);
    const float e = __expf(2.f * x);
    return (e - 1.f) / (e + 1.f);
}

// ---------------------------------------------------------------------------
// GEMM: C = act(A @ W + bias). A: [M][K] f16. Wt: [N][K] f16 (pre-transposed).
// M%128==0, N%128==0, K%32==0. 256 threads = 4 waves (2x2), 64x64 per wave.
// ---------------------------------------------------------------------------
template <bool TANH, bool OUTF16>
__global__ __launch_bounds__(256) void k_gemm_f16(const f16* __restrict__ A,
                                                  const f16* __restrict__ Wt,
                                                  const float* __restrict__ bias,
                                                  void* __restrict__ Cv,
                                                  int M, int N, int K)
{
    __shared__ __align__(16) f16 As[128][32];
    __shared__ __align__(16) f16 Bs[128][32];

    const int t  = threadIdx.x;
    const int l  = t & 63;
    const int wv = t >> 6;
    const int wr = wv >> 1, wc = wv & 1;
    const int lm = l & 15, lk = l >> 4;
    const int bm = blockIdx.y, bn = blockIdx.x;

    const f16* Ab = A  + (size_t)bm * 128 * K;
    const f16* Bb = Wt + (size_t)bn * 128 * K;
    char* sA = (char*)&As[0][0];
    char* sB = (char*)&Bs[0][0];
    const int wbase = wv * 64;

    f32x4 acc[4][4] = {};

    for (int k0 = 0; k0 < K; k0 += 32) {
        // stage 128x32 f16 tiles: 512 chunks of 16B each, 2 rounds x 256 thr
#pragma unroll
        for (int r = 0; r < 2; ++r) {
            const int c = r * 256 + t;                       // chunk id
            const size_t goff = (size_t)(c >> 2) * K + (size_t)k0 + (size_t)(c & 3) * 8;
            gl_lds16(Ab + goff, sA + (size_t)(r * 256 + wbase) * 16);
            gl_lds16(Bb + goff, sB + (size_t)(r * 256 + wbase) * 16);
        }
        __syncthreads();                                     // drains vmcnt

        f16x8 af[4], bf[4];
#pragma unroll
        for (int i = 0; i < 4; ++i) {
            af[i] = *reinterpret_cast<const f16x8*>(&As[wr * 64 + i * 16 + lm][lk * 8]);
            bf[i] = *reinterpret_cast<const f16x8*>(&Bs[wc * 64 + i * 16 + lm][lk * 8]);
        }
#pragma unroll
        for (int i = 0; i < 4; ++i)
#pragma unroll
            for (int j = 0; j < 4; ++j)
                acc[i][j] = __builtin_amdgcn_mfma_f32_16x16x32_f16(af[i], bf[j], acc[i][j], 0, 0, 0);
        __syncthreads();
    }

    // epilogue. C/D: col = lane&15, row = (lane>>4)*4 + q   (m89/m91 verified)
    const int row0 = bm * 128 + wr * 64;
    const int col0 = bn * 128 + wc * 64;
#pragma unroll
    for (int j = 0; j < 4; ++j) {
        const int col = col0 + j * 16 + lm;
        const float bv = bias[col];
#pragma unroll
        for (int i = 0; i < 4; ++i) {
#pragma unroll
            for (int q = 0; q < 4; ++q) {
                const int row = row0 + i * 16 + lk * 4 + q;
                float v = acc[i][j][q] + bv;
                if (TANH) v = fast_tanh(v);
                if (OUTF16) ((f16*)Cv)[(size_t)row * N + col] = (f16)v;
                else        ((float*)Cv)[(size_t)row * N + col] = v;
            }
        }
    }
}

// ---------------------------------------------------------------------------
// Weight transpose+convert: W f32 [K][N] -> Wt f16 [N][K].  K,N % 32 == 0.
// ---------------------------------------------------------------------------
__global__ __launch_bounds__(256) void k_wt(const float* __restrict__ W,
                                            f16* __restrict__ Wt, int K, int N)
{
    __shared__ float tl[32][33];
    const int n0 = blockIdx.x * 32, k0 = blockIdx.y * 32;
    const int tx = threadIdx.x & 31, ty = threadIdx.x >> 5;
#pragma unroll
    for (int i = 0; i < 32; i += 8)
        tl[ty + i][tx] = W[(size_t)(k0 + ty + i) * N + n0 + tx];
    __syncthreads();
#pragma unroll
    for (int i = 0; i < 32; i += 8)
        Wt[(size_t)(n0 + ty + i) * K + k0 + tx] = (f16)tl[tx][ty + i];
}

__global__ __launch_bounds__(256) void k_cvt(const float* __restrict__ in,
                                             f16* __restrict__ out, int n)
{
    const int i = blockIdx.x * 256 + threadIdx.x;
    if (i < n) out[i] = (f16)in[i];
}

// ---------------------------------------------------------------------------
// Gathers (window: (512,128,512) f32)
// ---------------------------------------------------------------------------
__global__ __launch_bounds__(256) void k_gather_x0(const float* __restrict__ win,
                                                   f16* __restrict__ out)
{
    const int i = blockIdx.x * 256 + threadIdx.x;     // 512*64 8-elem chunks
    if (i >= 512 * 64) return;
    const int b = i >> 6, c8 = i & 63;
    const float* s = win + (size_t)b * 65536 + c8 * 8;
    const float4 v0 = *reinterpret_cast<const float4*>(s);
    const float4 v1 = *reinterpret_cast<const float4*>(s + 4);
    f16x8 o;
    o[0] = (f16)v0.x; o[1] = (f16)v0.y; o[2] = (f16)v0.z; o[3] = (f16)v0.w;
    o[4] = (f16)v1.x; o[5] = (f16)v1.y; o[6] = (f16)v1.z; o[7] = (f16)v1.w;
    *reinterpret_cast<f16x8*>(out + (size_t)b * 512 + c8 * 8) = o;
}

__global__ __launch_bounds__(256) void k_gather_tgt(const float* __restrict__ win,
                                                    f16* __restrict__ out, int row0)
{
    const int i = blockIdx.x * 256 + threadIdx.x;     // M_CH*64 chunks
    if (i >= M_CH * 64) return;
    const int r = i >> 6, c8 = i & 63;
    const unsigned g = row0 + r;
    const unsigned b = g / 127u;
    const unsigned tt = g - b * 127u + 1u;
    const float* s = win + ((size_t)(b * 128u + tt)) * 512 + c8 * 8;
    const float4 v0 = *reinterpret_cast<const float4*>(s);
    const float4 v1 = *reinterpret_cast<const float4*>(s + 4);
    f16x8 o;
    o[0] = (f16)v0.x; o[1] = (f16)v0.y; o[2] = (f16)v0.z; o[3] = (f16)v0.w;
    o[4] = (f16)v1.x; o[5] = (f16)v1.y; o[6] = (f16)v1.z; o[7] = (f16)v1.w;
    *reinterpret_cast<f16x8*>(out + (size_t)r * 512 + c8 * 8) = o;
}

// ---------------------------------------------------------------------------
// Koopman closed form + loss_linear, and f16 dec-input write.
// ---------------------------------------------------------------------------
__device__ __forceinline__ void block_red_add(double s, double* acc)
{
    __shared__ double sm[256];
    sm[threadIdx.x] = s;
    __syncthreads();
    for (int o = 128; o > 0; o >>= 1) {
        if (threadIdx.x < (unsigned)o) sm[threadIdx.x] += sm[threadIdx.x + o];
        __syncthreads();
    }
    if (threadIdx.x == 0) atomicAdd(acc, sm[0]);
}

__global__ __launch_bounds__(256) void k_koop_loss(const float* __restrict__ pK,
                                                   const float* __restrict__ z0,
                                                   const float* __restrict__ zt,
                                                   int row0, f16* __restrict__ koopZ,
                                                   double* __restrict__ acc)
{
    const int idx = blockIdx.x * 256 + threadIdx.x;   // M_CH*64 pairs
    double s = 0.0;
    if (idx < M_CH * 64) {
        const int n = idx & 63;
        const int r = idx >> 6;
        const unsigned g = row0 + r;
        const unsigned b = g / 127u;
        const int j = (int)(g - b * 127u);
        const float2 z = *reinterpret_cast<const float2*>(z0 + (size_t)b * 128 + 2 * n);
        const float2 q = *reinterpret_cast<const float2*>(pK + (size_t)b * 128 + 2 * n);
        const float tf = KDT * (float)(j + 1);
        const float e  = expf(q.x * tf);
        const float cs = cosf(q.y * tf);
        const float sn = sinf(q.y * tf);
        const float zp0 = e * (cs * z.x - sn * z.y);
        const float zp1 = e * (sn * z.x + cs * z.y);
        koopZ[(size_t)r * 128 + 2 * n]     = (f16)zp0;
        koopZ[(size_t)r * 128 + 2 * n + 1] = (f16)zp1;
        const float2 zv = *reinterpret_cast<const float2*>(zt + (size_t)r * 128 + 2 * n);
        const float d0 = zp0 - zv.x, d1 = zp1 - zv.y;
        s = (double)d0 * d0 + (double)d1 * d1;
    }
    block_red_add(s, acc);
}

// ---------------------------------------------------------------------------
// Losses vs window
// ---------------------------------------------------------------------------
__global__ __launch_bounds__(256) void k_sqdiff_recon(const float* __restrict__ x0r,
                                                      const float* __restrict__ win,
                                                      double* __restrict__ acc)
{
    const int i = blockIdx.x * 256 + threadIdx.x;     // 512*128 float4s
    double s = 0.0;
    if (i < 512 * 128) {
        const int b = i >> 7, c4 = i & 127;
        const float4 x = *reinterpret_cast<const float4*>(x0r + (size_t)b * 512 + c4 * 4);
        const float4 y = *reinterpret_cast<const float4*>(win + (size_t)b * 65536 + c4 * 4);
        const float d0 = x.x - y.x, d1 = x.y - y.y, d2 = x.z - y.z, d3 = x.w - y.w;
        s = (double)d0 * d0 + (double)d1 * d1 + (double)d2 * d2 + (double)d3 * d3;
    }
    block_red_add(s, acc);
}

__global__ __launch_bounds__(256) void k_sqdiff_tgt(const float* __restrict__ xp,
                                                    const float* __restrict__ win,
                                                    int row0, double* __restrict__ acc)
{
    const int i = blockIdx.x * 256 + threadIdx.x;     // M_CH*128 float4s
    double s = 0.0;
    if (i < M_CH * 128) {
        const int r = i >> 7, c4 = i & 127;
        const unsigned g = row0 + r;
        const unsigned b = g / 127u;
        const unsigned tt = g - b * 127u + 1u;
        const float4 x = *reinterpret_cast<const float4*>(xp + (size_t)r * 512 + c4 * 4);
        const float4 y = *reinterpret_cast<const float4*>(win + ((size_t)(b * 128u + tt)) * 512 + c4 * 4);
        const float d0 = x.x - y.x, d1 = x.y - y.y, d2 = x.z - y.z, d3 = x.w - y.w;
        s = (double)d0 * d0 + (double)d1 * d1 + (double)d2 * d2 + (double)d3 * d3;
    }
    block_red_add(s, acc);
}

__global__ void k_finalize(const double* __restrict__ acc, float* __restrict__ out)
{
    if (threadIdx.x == 0 && blockIdx.x == 0) {
        const double recon  = acc[0] / (512.0 * 512.0);
        const double linear = acc[1] / (65024.0 * 128.0);
        const double pred   = acc[2] / (65024.0 * 512.0);
        out[0] = (float)(recon + linear + pred);
        out[1] = (float)recon;
        out[2] = (float)linear;
        out[3] = (float)pred;
    }
}

// ---------------------------------------------------------------------------
extern "C" void kernel_launch(void* const* d_in, const int* in_sizes, int n_in,
                              void* d_out, int out_size, void* d_ws, size_t ws_size,
                              hipStream_t stream)
{
    const float* window = (const float*)d_in[0];
    const float* eW1 = (const float*)d_in[1];
    const float* eb1 = (const float*)d_in[2];
    const float* eW2 = (const float*)d_in[3];
    const float* eb2 = (const float*)d_in[4];
    const float* eW3 = (const float*)d_in[5];
    const float* eb3 = (const float*)d_in[6];
    const float* dW1 = (const float*)d_in[7];
    const float* db1 = (const float*)d_in[8];
    const float* dW2 = (const float*)d_in[9];
    const float* db2 = (const float*)d_in[10];
    const float* dW3 = (const float*)d_in[11];
    const float* db3 = (const float*)d_in[12];
    const float* kW1 = (const float*)d_in[13];
    const float* kb1 = (const float*)d_in[14];
    const float* kW2 = (const float*)d_in[15];
    const float* kb2 = (const float*)d_in[16];
    float* out = (float*)d_out;
    (void)in_sizes; (void)n_in; (void)out_size; (void)ws_size;

    char* p = (char*)d_ws;
    size_t off = 256;                       // [0,32): 3 double accumulators
    double* acc = (double*)p;
    auto takeB = [&](size_t bytes) -> char* {
        char* r = p + off;
        off += (bytes + 255) & ~(size_t)255;
        return r;
    };
    f16* eW1t = (f16*)takeB((size_t)512 * 1024 * 2);
    f16* eW2t = (f16*)takeB((size_t)1024 * 1024 * 2);
    f16* eW3t = (f16*)takeB((size_t)1024 * 128 * 2);
    f16* dW1t = (f16*)takeB((size_t)128 * 1024 * 2);
    f16* dW2t = (f16*)takeB((size_t)1024 * 1024 * 2);
    f16* dW3t = (f16*)takeB((size_t)1024 * 512 * 2);
    f16* kW1t = (f16*)takeB((size_t)128 * 128 * 2);
    f16* kW2t = (f16*)takeB((size_t)128 * 128 * 2);
    f16* x0f16 = (f16*)takeB((size_t)512 * 512 * 2);
    float* z0f32 = (float*)takeB((size_t)65536 * 4);
    f16* z0f16 = (f16*)takeB((size_t)65536 * 2);
    f16* hK = (f16*)takeB((size_t)65536 * 2);
    float* pK = (float*)takeB((size_t)65536 * 4);
    float* x0r = (float*)takeB((size_t)512 * 512 * 4);
    f16* cH1 = (f16*)takeB((size_t)M_CH * 1024 * 2);
    f16* cH2 = (f16*)takeB((size_t)M_CH * 1024 * 2);
    // overlap region: [cIn f16 | cZ f32 | koopZ f16] reused by cX f32
    char* region = takeB((size_t)M_CH * 512 * 4);       // 33,292,288 B
    f16* cIn = (f16*)region;                            // 16,646,144 B
    float* cZ = (float*)(region + (size_t)M_CH * 512 * 2);          // 8,323,072 B
    f16* koopZ = (f16*)(region + (size_t)M_CH * 512 * 2 + (size_t)M_CH * 128 * 4);
    float* cX = (float*)region;                         // aliases all three (dead by then)

    hipMemsetAsync(acc, 0, 32, stream);

    auto G = [&](const f16* A, const f16* Wt, const float* b, void* C,
                 int M, int N, int K, bool tanh_, bool f16out) {
        dim3 grid(N / 128, M / 128);
        if (tanh_) {
            if (f16out) k_gemm_f16<true, true ><<<grid, 256, 0, stream>>>(A, Wt, b, C, M, N, K);
            else        k_gemm_f16<true, false><<<grid, 256, 0, stream>>>(A, Wt, b, C, M, N, K);
        } else {
            if (f16out) k_gemm_f16<false, true ><<<grid, 256, 0, stream>>>(A, Wt, b, C, M, N, K);
            else        k_gemm_f16<false, false><<<grid, 256, 0, stream>>>(A, Wt, b, C, M, N, K);
        }
    };
    auto WT = [&](const float* W, f16* Wt, int K, int N) {
        k_wt<<<dim3(N / 32, K / 32), 256, 0, stream>>>(W, Wt, K, N);
    };

    // weight prep
    WT(eW1, eW1t, 512, 1024);  WT(eW2, eW2t, 1024, 1024); WT(eW3, eW3t, 1024, 128);
    WT(dW1, dW1t, 128, 1024);  WT(dW2, dW2t, 1024, 1024); WT(dW3, dW3t, 1024, 512);
    WT(kW1, kW1t, 128, 128);   WT(kW2, kW2t, 128, 128);

    // x0 path
    k_gather_x0<<<(512 * 64 + 255) / 256, 256, 0, stream>>>(window, x0f16);
    G(x0f16, eW1t, eb1, cH1, 512, 1024, 512, true, true);
    G(cH1,   eW2t, eb2, cH2, 512, 1024, 1024, true, true);
    G(cH2,   eW3t, eb3, z0f32, 512, 128, 1024, false, false);
    k_cvt<<<(65536 + 255) / 256, 256, 0, stream>>>(z0f32, z0f16, 65536);
    G(z0f16, dW1t, db1, cH1, 512, 1024, 128, true, true);
    G(cH1,   dW2t, db2, cH2, 512, 1024, 1024, true, true);
    G(cH2,   dW3t, db3, x0r, 512, 512, 1024, false, false);
    k_sqdiff_recon<<<(512 * 128 + 255) / 256, 256, 0, stream>>>(x0r, window, acc + 0);

    // koopman params
    G(z0f16, kW1t, kb1, hK, 512, 128, 128, true, true);
    G(hK,    kW2t, kb2, pK, 512, 128, 128, false, false);

    // big stacks: 4 chunks of 16256 rows
    for (int c = 0; c < 4; ++c) {
        const int row0 = c * M_CH;
        k_gather_tgt<<<(M_CH * 64 + 255) / 256, 256, 0, stream>>>(window, cIn, row0);
        G(cIn, eW1t, eb1, cH1, M_CH, 1024, 512, true, true);
        G(cH1, eW2t, eb2, cH2, M_CH, 1024, 1024, true, true);
        G(cH2, eW3t, eb3, cZ, M_CH, 128, 1024, false, false);
        k_koop_loss<<<(M_CH * 64 + 255) / 256, 256, 0, stream>>>(pK, z0f32, cZ, row0, koopZ, acc + 1);
        G(koopZ, dW1t, db1, cH1, M_CH, 1024, 128, true, true);
        G(cH1,   dW2t, db2, cH2, M_CH, 1024, 1024, true, true);
        G(cH2,   dW3t, db3, cX, M_CH, 512, 1024, false, false);
        k_sqdiff_tgt<<<(M_CH * 128 + 255) / 256, 256, 0, stream>>>(cX, window, row0, acc + 2);
    }

    k_finalize<<<1, 64, 0, stream>>>(acc, out);
}

// Round 5
// 1892.857 us; speedup vs baseline: 3.6612x; 1.0509x over previous
//
#include <hip/hip_runtime.h>
#include <cstddef>
#include <cstdint>

// DynamicAutoencoder — Round 3 kernel (2nd resubmit; prior rounds hit broker
// infra failures, no measurement). Unified row space (b,t), fused loss
// epilogues, zero atomics.
//   rows g = b*128 + t, g in [0,65536). 4 chunks of 16384 rows.
//   enc on all rows; enc3 epilogue: t==0 -> dec_in = z0-row (f16)
//                                   t>=1 -> z_pred closed form, linear loss,
//                                           dec_in = z_pred (f16)
//   dec on dec_in;  dec3 epilogue: d = v - window[g][col]; t==0 -> recon loss
//                                   t>=1 -> pred loss
//   per-block partial sums -> slot array -> finalize kernel. No atomics.
//   GEMM: 128x128 tile, BK=32, 4 waves, mfma_f32_16x16x32_f16, gl_lds width 16.

#define KDT 0.01f
#define CH 16384            // rows per chunk (= 128 * 128)
#define NCHUNK 4

typedef _Float16 f16;
typedef f16 f16x8 __attribute__((ext_vector_type(8)));
typedef float f32x4 __attribute__((ext_vector_type(4)));

typedef __attribute__((address_space(1))) const unsigned int gu32;
typedef __attribute__((address_space(3))) unsigned int lu32;

__device__ __forceinline__ void gl_lds16(const void* g, void* l) {
    __builtin_amdgcn_global_load_lds((gu32*)g, (lu32*)l, 16, 0, 0);
}

__device__ __forceinline__ float fast_tanh(float x) {
    x = fminf(fmaxf(x, -15.f), 15.f);
    const float e = __expf(2.f * x);
    return (e - 1.f) / (e + 1.f);
}

// partial-sum slot layout (doubles): [0,512) lin | [512,2560) rec | [2560,4608) pred
#define PB_LIN 0
#define PB_REC 512
#define PB_PRED 2560
#define PB_TOTAL 4608

// ---------------------------------------------------------------------------
// GEMM: C = act(A @ Wt^T + bias). A: [M][K] f16, Wt: [N][K] f16.
// MODE 0: store (f16 or f32). MODE 1: enc3 fused (koop + linear loss + dec_in).
// MODE 2: dec3 fused (recon/pred loss vs window). M%128==0, N%128==0, K%32==0.
// ---------------------------------------------------------------------------
template <int MODE, bool TANH, bool OUTF16>
__global__ __launch_bounds__(256) void k_gemm_f16(const f16* __restrict__ A,
                                                  const f16* __restrict__ Wt,
                                                  const float* __restrict__ bias,
                                                  void* __restrict__ Cv,
                                                  int M, int N, int K,
                                                  const float* __restrict__ win,
                                                  int g0,
                                                  const float* __restrict__ pK,
                                                  const float* __restrict__ z0,
                                                  f16* __restrict__ decin,
                                                  double* __restrict__ p0,
                                                  double* __restrict__ p1)
{
    __shared__ __align__(16) f16 As[128][32];
    __shared__ __align__(16) f16 Bs[128][32];
    __shared__ double sm[256];

    const int t  = threadIdx.x;
    const int l  = t & 63;
    const int wv = t >> 6;
    const int wr = wv >> 1, wc = wv & 1;
    const int lm = l & 15, lk = l >> 4;
    const int bm = blockIdx.y, bn = blockIdx.x;

    const f16* Ab = A  + (size_t)bm * 128 * K;
    const f16* Bb = Wt + (size_t)bn * 128 * K;
    char* sA = (char*)&As[0][0];
    char* sB = (char*)&Bs[0][0];
    const int wbase = wv * 64;

    f32x4 acc[4][4] = {};

    for (int k0 = 0; k0 < K; k0 += 32) {
#pragma unroll
        for (int r = 0; r < 2; ++r) {
            const int c = r * 256 + t;
            const size_t goff = (size_t)(c >> 2) * K + (size_t)k0 + (size_t)(c & 3) * 8;
            gl_lds16(Ab + goff, sA + (size_t)(r * 256 + wbase) * 16);
            gl_lds16(Bb + goff, sB + (size_t)(r * 256 + wbase) * 16);
        }
        __syncthreads();

        f16x8 af[4], bf[4];
#pragma unroll
        for (int i = 0; i < 4; ++i) {
            af[i] = *reinterpret_cast<const f16x8*>(&As[wr * 64 + i * 16 + lm][lk * 8]);
            bf[i] = *reinterpret_cast<const f16x8*>(&Bs[wc * 64 + i * 16 + lm][lk * 8]);
        }
#pragma unroll
        for (int i = 0; i < 4; ++i)
#pragma unroll
            for (int j = 0; j < 4; ++j)
                acc[i][j] = __builtin_amdgcn_mfma_f32_16x16x32_f16(af[i], bf[j], acc[i][j], 0, 0, 0);
        __syncthreads();
    }

    // C/D fragment: col = lane&15 (+j*16), row = (lane>>4)*4 + q (+i*16)
    const int col0 = bn * 128 + wc * 64;

    if (MODE == 0) {
        const int row0 = bm * 128 + wr * 64;
#pragma unroll
        for (int j = 0; j < 4; ++j) {
            const int col = col0 + j * 16 + lm;
            const float bv = bias[col];
#pragma unroll
            for (int i = 0; i < 4; ++i)
#pragma unroll
                for (int q = 0; q < 4; ++q) {
                    const int row = row0 + i * 16 + lk * 4 + q;
                    float v = acc[i][j][q] + bv;
                    if (TANH) v = fast_tanh(v);
                    if (OUTF16) ((f16*)Cv)[(size_t)row * N + col] = (f16)v;
                    else        ((float*)Cv)[(size_t)row * N + col] = v;
                }
        }
    } else {
        double s0 = 0.0, s1 = 0.0;
#pragma unroll
        for (int i = 0; i < 4; ++i) {
#pragma unroll
            for (int q = 0; q < 4; ++q) {
                const int rl = bm * 128 + wr * 64 + i * 16 + lk * 4 + q;  // row in chunk
                const int g  = g0 + rl;                                   // global row
                const int tt = g & 127;                                   // timestep
                const int bb = g >> 7;                                    // batch
#pragma unroll
                for (int j = 0; j < 4; ++j) {
                    const int col = col0 + j * 16 + lm;
                    const float v = acc[i][j][q] + bias[col];
                    if (MODE == 1) {
                        if (tt == 0) {
                            decin[(size_t)rl * 128 + col] = (f16)v;
                        } else {
                            const int pair = (bb << 7) + (col & ~1);
                            const float2 zz = *reinterpret_cast<const float2*>(z0 + pair);
                            const float2 qq = *reinterpret_cast<const float2*>(pK + pair);
                            const float tf = KDT * (float)tt;
                            const float e  = expf(qq.x * tf);
                            const float cs = cosf(qq.y * tf);
                            const float sn = sinf(qq.y * tf);
                            const float zp = (col & 1) ? e * (sn * zz.x + cs * zz.y)
                                                       : e * (cs * zz.x - sn * zz.y);
                            decin[(size_t)rl * 128 + col] = (f16)zp;
                            const float d = zp - v;
                            s0 += (double)d * d;
                        }
                    } else {  // MODE 2
                        const float d = v - win[(size_t)g * 512 + col];
                        if (tt == 0) s0 += (double)d * d;
                        else         s1 += (double)d * d;
                    }
                }
            }
        }
        const int bid = blockIdx.y * gridDim.x + blockIdx.x;
        sm[t] = s0;
        __syncthreads();
        for (int o = 128; o > 0; o >>= 1) {
            if (t < o) sm[t] += sm[t + o];
            __syncthreads();
        }
        if (t == 0) p0[bid] = sm[0];
        if (MODE == 2) {
            __syncthreads();
            sm[t] = s1;
            __syncthreads();
            for (int o = 128; o > 0; o >>= 1) {
                if (t < o) sm[t] += sm[t + o];
                __syncthreads();
            }
            if (t == 0) p1[bid] = sm[0];
        }
    }
}

// ---------------------------------------------------------------------------
// Weight transpose+convert: W f32 [K][N] -> Wt f16 [N][K].
// ---------------------------------------------------------------------------
__global__ __launch_bounds__(256) void k_wt(const float* __restrict__ W,
                                            f16* __restrict__ Wt, int K, int N)
{
    __shared__ float tl[32][33];
    const int n0 = blockIdx.x * 32, k0 = blockIdx.y * 32;
    const int tx = threadIdx.x & 31, ty = threadIdx.x >> 5;
#pragma unroll
    for (int i = 0; i < 32; i += 8)
        tl[ty + i][tx] = W[(size_t)(k0 + ty + i) * N + n0 + tx];
    __syncthreads();
#pragma unroll
    for (int i = 0; i < 32; i += 8)
        Wt[(size_t)(n0 + ty + i) * K + k0 + tx] = (f16)tl[tx][ty + i];
}

__global__ __launch_bounds__(256) void k_cvt(const float* __restrict__ in,
                                             f16* __restrict__ out, int n)
{
    const int i = blockIdx.x * 256 + threadIdx.x;
    if (i < n) out[i] = (f16)in[i];
}

// ---------------------------------------------------------------------------
// Gathers (window: (512,128,512) f32)
// ---------------------------------------------------------------------------
__global__ __launch_bounds__(256) void k_gather_x0(const float* __restrict__ win,
                                                   f16* __restrict__ out)
{
    const int i = blockIdx.x * 256 + threadIdx.x;     // 512*64 8-elem chunks
    if (i >= 512 * 64) return;
    const int b = i >> 6, c8 = i & 63;
    const float* s = win + (size_t)b * 65536 + c8 * 8;
    const float4 v0 = *reinterpret_cast<const float4*>(s);
    const float4 v1 = *reinterpret_cast<const float4*>(s + 4);
    f16x8 o;
    o[0] = (f16)v0.x; o[1] = (f16)v0.y; o[2] = (f16)v0.z; o[3] = (f16)v0.w;
    o[4] = (f16)v1.x; o[5] = (f16)v1.y; o[6] = (f16)v1.z; o[7] = (f16)v1.w;
    *reinterpret_cast<f16x8*>(out + (size_t)b * 512 + c8 * 8) = o;
}

// contiguous rows g0..g0+CH -> f16
__global__ __launch_bounds__(256) void k_gather_all(const float* __restrict__ win,
                                                    f16* __restrict__ out, int g0)
{
    const int i = blockIdx.x * 256 + threadIdx.x;     // CH*64 8-elem chunks
    if (i >= CH * 64) return;
    const int r = i >> 6, c8 = i & 63;
    const float* s = win + ((size_t)(g0 + r)) * 512 + c8 * 8;
    const float4 v0 = *reinterpret_cast<const float4*>(s);
    const float4 v1 = *reinterpret_cast<const float4*>(s + 4);
    f16x8 o;
    o[0] = (f16)v0.x; o[1] = (f16)v0.y; o[2] = (f16)v0.z; o[3] = (f16)v0.w;
    o[4] = (f16)v1.x; o[5] = (f16)v1.y; o[6] = (f16)v1.z; o[7] = (f16)v1.w;
    *reinterpret_cast<f16x8*>(out + (size_t)r * 512 + c8 * 8) = o;
}

// ---------------------------------------------------------------------------
__global__ __launch_bounds__(256) void k_finalize(const double* __restrict__ pb,
                                                  float* __restrict__ out)
{
    __shared__ double sm[256];
    const int t = threadIdx.x;
    double a0 = 0.0, a1 = 0.0, a2 = 0.0;
    for (int i = t; i < 512; i += 256)  a0 += pb[PB_LIN + i];
    for (int i = t; i < 2048; i += 256) a1 += pb[PB_REC + i];
    for (int i = t; i < 2048; i += 256) a2 += pb[PB_PRED + i];

    double r[3];
    double v[3] = {a0, a1, a2};
    for (int k = 0; k < 3; ++k) {
        sm[t] = v[k];
        __syncthreads();
        for (int o = 128; o > 0; o >>= 1) {
            if (t < o) sm[t] += sm[t + o];
            __syncthreads();
        }
        r[k] = sm[0];
        __syncthreads();
    }
    if (t == 0) {
        const double linear = r[0] / (65024.0 * 128.0);
        const double recon  = r[1] / (512.0 * 512.0);
        const double pred   = r[2] / (65024.0 * 512.0);
        out[0] = (float)(recon + linear + pred);
        out[1] = (float)recon;
        out[2] = (float)linear;
        out[3] = (float)pred;
    }
}

// ---------------------------------------------------------------------------
extern "C" void kernel_launch(void* const* d_in, const int* in_sizes, int n_in,
                              void* d_out, int out_size, void* d_ws, size_t ws_size,
                              hipStream_t stream)
{
    const float* window = (const float*)d_in[0];
    const float* eW1 = (const float*)d_in[1];
    const float* eb1 = (const float*)d_in[2];
    const float* eW2 = (const float*)d_in[3];
    const float* eb2 = (const float*)d_in[4];
    const float* eW3 = (const float*)d_in[5];
    const float* eb3 = (const float*)d_in[6];
    const float* dW1 = (const float*)d_in[7];
    const float* db1 = (const float*)d_in[8];
    const float* dW2 = (const float*)d_in[9];
    const float* db2 = (const float*)d_in[10];
    const float* dW3 = (const float*)d_in[11];
    const float* db3 = (const float*)d_in[12];
    const float* kW1 = (const float*)d_in[13];
    const float* kb1 = (const float*)d_in[14];
    const float* kW2 = (const float*)d_in[15];
    const float* kb2 = (const float*)d_in[16];
    float* out = (float*)d_out;
    (void)in_sizes; (void)n_in; (void)out_size; (void)ws_size;

    char* p = (char*)d_ws;
    size_t off = 0;
    auto takeB = [&](size_t bytes) -> char* {
        char* r = p + off;
        off += (bytes + 255) & ~(size_t)255;
        return r;
    };
    double* pb = (double*)takeB(PB_TOTAL * 8);
    f16* eW1t = (f16*)takeB((size_t)512 * 1024 * 2);
    f16* eW2t = (f16*)takeB((size_t)1024 * 1024 * 2);
    f16* eW3t = (f16*)takeB((size_t)1024 * 128 * 2);
    f16* dW1t = (f16*)takeB((size_t)128 * 1024 * 2);
    f16* dW2t = (f16*)takeB((size_t)1024 * 1024 * 2);
    f16* dW3t = (f16*)takeB((size_t)1024 * 512 * 2);
    f16* kW1t = (f16*)takeB((size_t)128 * 128 * 2);
    f16* kW2t = (f16*)takeB((size_t)128 * 128 * 2);
    f16* x0f16 = (f16*)takeB((size_t)512 * 512 * 2);
    float* z0f32 = (float*)takeB((size_t)65536 * 4);
    f16* z0f16 = (f16*)takeB((size_t)65536 * 2);
    f16* hK = (f16*)takeB((size_t)65536 * 2);
    float* pKbuf = (float*)takeB((size_t)65536 * 4);
    f16* cIn = (f16*)takeB((size_t)CH * 512 * 2);
    f16* cH1 = (f16*)takeB((size_t)CH * 1024 * 2);
    f16* cH2 = (f16*)takeB((size_t)CH * 1024 * 2);
    f16* decin = (f16*)takeB((size_t)CH * 128 * 2);

    hipMemsetAsync(pb, 0, PB_TOTAL * 8, stream);

    auto G = [&](const f16* A, const f16* Wt, const float* b, void* C,
                 int M, int N, int K, bool tanh_, bool f16out) {
        dim3 grid(N / 128, M / 128);
        if (tanh_) k_gemm_f16<0, true, true ><<<grid, 256, 0, stream>>>(A, Wt, b, C, M, N, K,
                       nullptr, 0, nullptr, nullptr, nullptr, nullptr, nullptr);
        else if (f16out) k_gemm_f16<0, false, true ><<<grid, 256, 0, stream>>>(A, Wt, b, C, M, N, K,
                       nullptr, 0, nullptr, nullptr, nullptr, nullptr, nullptr);
        else k_gemm_f16<0, false, false><<<grid, 256, 0, stream>>>(A, Wt, b, C, M, N, K,
                       nullptr, 0, nullptr, nullptr, nullptr, nullptr, nullptr);
    };
    auto WT = [&](const float* W, f16* Wt, int K, int N) {
        k_wt<<<dim3(N / 32, K / 32), 256, 0, stream>>>(W, Wt, K, N);
    };

    // weight prep
    WT(eW1, eW1t, 512, 1024);  WT(eW2, eW2t, 1024, 1024); WT(eW3, eW3t, 1024, 128);
    WT(dW1, dW1t, 128, 1024);  WT(dW2, dW2t, 1024, 1024); WT(dW3, dW3t, 1024, 512);
    WT(kW1, kW1t, 128, 128);   WT(kW2, kW2t, 128, 128);

    // mini path: z0 + koopman params
    k_gather_x0<<<128, 256, 0, stream>>>(window, x0f16);
    G(x0f16, eW1t, eb1, cH1, 512, 1024, 512, true, true);
    G(cH1,   eW2t, eb2, cH2, 512, 1024, 1024, true, true);
    G(cH2,   eW3t, eb3, z0f32, 512, 128, 1024, false, false);
    k_cvt<<<256, 256, 0, stream>>>(z0f32, z0f16, 65536);
    G(z0f16, kW1t, kb1, hK, 512, 128, 128, true, true);
    G(hK,    kW2t, kb2, pKbuf, 512, 128, 128, false, false);

    // unified stacks: 4 chunks of 16384 rows over (b,t)
    for (int c = 0; c < NCHUNK; ++c) {
        const int g0 = c * CH;
        k_gather_all<<<CH * 64 / 256, 256, 0, stream>>>(window, cIn, g0);
        G(cIn, eW1t, eb1, cH1, CH, 1024, 512, true, true);
        G(cH1, eW2t, eb2, cH2, CH, 1024, 1024, true, true);
        // enc3 fused: linear loss + dec_in build
        k_gemm_f16<1, false, true><<<dim3(1, CH / 128), 256, 0, stream>>>(
            cH2, eW3t, eb3, nullptr, CH, 128, 1024,
            nullptr, g0, pKbuf, z0f32, decin, pb + PB_LIN + c * 128, nullptr);
        G(decin, dW1t, db1, cH1, CH, 1024, 128, true, true);
        G(cH1,   dW2t, db2, cH2, CH, 1024, 1024, true, true);
        // dec3 fused: recon + pred loss vs window
        k_gemm_f16<2, false, false><<<dim3(4, CH / 128), 256, 0, stream>>>(
            cH2, dW3t, db3, nullptr, CH, 512, 1024,
            window, g0, nullptr, nullptr, nullptr,
            pb + PB_REC + c * 512, pb + PB_PRED + c * 512);
    }

    k_finalize<<<1, 256, 0, stream>>>(pb, out);
}

// Round 7
// 1283.520 us; speedup vs baseline: 5.3994x; 1.4747x over previous
//
#include <hip/hip_runtime.h>
#include <cstddef>
#include <cstdint>

// DynamicAutoencoder — Round 6 kernel (resubmit; broker timeout, no data).
// De-fused koopman (R5: fused enc3 epilogue was 38% of runtime at 5.8% occ).
//   Phase A (x4 chunks): gather -> enc1 -> enc2 -> enc3 (f32 out, all 65536 rows -> cZfull)
//   Phase B: gather z0 rows from cZfull; koopman MLP (2 small GEMMs) -> pK
//   Phase C (x4 chunks): k_koop (koopman closed form + linear loss + decin f16)
//                        -> dec1 -> dec2 -> dec3 (fused recon/pred loss)
//   Partial sums to unique slots, no atomics. GEMM: 128x128, BK=32, 4 waves,
//   mfma_f32_16x16x32_f16, global_load_lds width 16.

#define KDT 0.01f
#define CH 16384
#define NCHUNK 4

typedef _Float16 f16;
typedef f16 f16x8 __attribute__((ext_vector_type(8)));
typedef f16 f16x4 __attribute__((ext_vector_type(4)));
typedef float f32x4 __attribute__((ext_vector_type(4)));

typedef __attribute__((address_space(1))) const unsigned int gu32;
typedef __attribute__((address_space(3))) unsigned int lu32;

__device__ __forceinline__ void gl_lds16(const void* g, void* l) {
    __builtin_amdgcn_global_load_lds((gu32*)g, (lu32*)l, 16, 0, 0);
}

__device__ __forceinline__ float fast_tanh(float x) {
    x = fminf(fmaxf(x, -15.f), 15.f);
    const float e = __expf(2.f * x);
    return (e - 1.f) / (e + 1.f);
}

// partial-sum slots (doubles): lin [0,4096) | rec [4096,6144) | pred [6144,8192)
#define PB_LIN 0
#define PB_REC 4096
#define PB_PRED 6144
#define PB_TOTAL 8192

// ---------------------------------------------------------------------------
// GEMM: C = act(A @ Wt^T + bias). A: [M][K] f16, Wt: [N][K] f16.
// MODE 0: store f16/f32. MODE 2: dec3 fused recon/pred loss vs window.
// ---------------------------------------------------------------------------
template <int MODE, bool TANH, bool OUTF16>
__global__ __launch_bounds__(256) void k_gemm_f16(const f16* __restrict__ A,
                                                  const f16* __restrict__ Wt,
                                                  const float* __restrict__ bias,
                                                  void* __restrict__ Cv,
                                                  int M, int N, int K,
                                                  const float* __restrict__ win,
                                                  int g0,
                                                  double* __restrict__ p0,
                                                  double* __restrict__ p1)
{
    __shared__ __align__(16) f16 As[128][32];
    __shared__ __align__(16) f16 Bs[128][32];
    __shared__ double sm[256];

    const int t  = threadIdx.x;
    const int l  = t & 63;
    const int wv = t >> 6;
    const int wr = wv >> 1, wc = wv & 1;
    const int lm = l & 15, lk = l >> 4;
    const int bm = blockIdx.y, bn = blockIdx.x;

    const f16* Ab = A  + (size_t)bm * 128 * K;
    const f16* Bb = Wt + (size_t)bn * 128 * K;
    char* sA = (char*)&As[0][0];
    char* sB = (char*)&Bs[0][0];
    const int wbase = wv * 64;

    f32x4 acc[4][4] = {};

    for (int k0 = 0; k0 < K; k0 += 32) {
#pragma unroll
        for (int r = 0; r < 2; ++r) {
            const int c = r * 256 + t;
            const size_t goff = (size_t)(c >> 2) * K + (size_t)k0 + (size_t)(c & 3) * 8;
            gl_lds16(Ab + goff, sA + (size_t)(r * 256 + wbase) * 16);
            gl_lds16(Bb + goff, sB + (size_t)(r * 256 + wbase) * 16);
        }
        __syncthreads();

        f16x8 af[4], bf[4];
#pragma unroll
        for (int i = 0; i < 4; ++i) {
            af[i] = *reinterpret_cast<const f16x8*>(&As[wr * 64 + i * 16 + lm][lk * 8]);
            bf[i] = *reinterpret_cast<const f16x8*>(&Bs[wc * 64 + i * 16 + lm][lk * 8]);
        }
#pragma unroll
        for (int i = 0; i < 4; ++i)
#pragma unroll
            for (int j = 0; j < 4; ++j)
                acc[i][j] = __builtin_amdgcn_mfma_f32_16x16x32_f16(af[i], bf[j], acc[i][j], 0, 0, 0);
        __syncthreads();
    }

    // C/D fragment: col = lane&15 (+j*16), row = (lane>>4)*4 + q (+i*16)
    const int col0 = bn * 128 + wc * 64;

    if (MODE == 0) {
        const int row0 = bm * 128 + wr * 64;
#pragma unroll
        for (int j = 0; j < 4; ++j) {
            const int col = col0 + j * 16 + lm;
            const float bv = bias[col];
#pragma unroll
            for (int i = 0; i < 4; ++i)
#pragma unroll
                for (int q = 0; q < 4; ++q) {
                    const int row = row0 + i * 16 + lk * 4 + q;
                    float v = acc[i][j][q] + bv;
                    if (TANH) v = fast_tanh(v);
                    if (OUTF16) ((f16*)Cv)[(size_t)row * N + col] = (f16)v;
                    else        ((float*)Cv)[(size_t)row * N + col] = v;
                }
        }
    } else {  // MODE 2: loss vs window, no store
        double s0 = 0.0, s1 = 0.0;
#pragma unroll
        for (int i = 0; i < 4; ++i) {
#pragma unroll
            for (int q = 0; q < 4; ++q) {
                const int rl = bm * 128 + wr * 64 + i * 16 + lk * 4 + q;
                const int g  = g0 + rl;
                const int tt = g & 127;
#pragma unroll
                for (int j = 0; j < 4; ++j) {
                    const int col = col0 + j * 16 + lm;
                    const float v = acc[i][j][q] + bias[col];
                    const float d = v - win[(size_t)g * 512 + col];
                    if (tt == 0) s0 += (double)d * d;
                    else         s1 += (double)d * d;
                }
            }
        }
        const int bid = blockIdx.y * gridDim.x + blockIdx.x;
        sm[t] = s0;
        __syncthreads();
        for (int o = 128; o > 0; o >>= 1) {
            if (t < o) sm[t] += sm[t + o];
            __syncthreads();
        }
        if (t == 0) p0[bid] = sm[0];
        __syncthreads();
        sm[t] = s1;
        __syncthreads();
        for (int o = 128; o > 0; o >>= 1) {
            if (t < o) sm[t] += sm[t + o];
            __syncthreads();
        }
        if (t == 0) p1[bid] = sm[0];
    }
}

// ---------------------------------------------------------------------------
// Weight transpose+convert: W f32 [K][N] -> Wt f16 [N][K].
// ---------------------------------------------------------------------------
__global__ __launch_bounds__(256) void k_wt(const float* __restrict__ W,
                                            f16* __restrict__ Wt, int K, int N)
{
    __shared__ float tl[32][33];
    const int n0 = blockIdx.x * 32, k0 = blockIdx.y * 32;
    const int tx = threadIdx.x & 31, ty = threadIdx.x >> 5;
#pragma unroll
    for (int i = 0; i < 32; i += 8)
        tl[ty + i][tx] = W[(size_t)(k0 + ty + i) * N + n0 + tx];
    __syncthreads();
#pragma unroll
    for (int i = 0; i < 32; i += 8)
        Wt[(size_t)(n0 + ty + i) * K + k0 + tx] = (f16)tl[tx][ty + i];
}

// ---------------------------------------------------------------------------
// window rows g0..g0+CH -> f16 (contiguous copy+convert)
// ---------------------------------------------------------------------------
__global__ __launch_bounds__(256) void k_gather_all(const float* __restrict__ win,
                                                    f16* __restrict__ out, int g0)
{
    const int i = blockIdx.x * 256 + threadIdx.x;     // CH*64 8-elem chunks
    if (i >= CH * 64) return;
    const int r = i >> 6, c8 = i & 63;
    const float* s = win + ((size_t)(g0 + r)) * 512 + c8 * 8;
    const float4 v0 = *reinterpret_cast<const float4*>(s);
    const float4 v1 = *reinterpret_cast<const float4*>(s + 4);
    f16x8 o;
    o[0] = (f16)v0.x; o[1] = (f16)v0.y; o[2] = (f16)v0.z; o[3] = (f16)v0.w;
    o[4] = (f16)v1.x; o[5] = (f16)v1.y; o[6] = (f16)v1.z; o[7] = (f16)v1.w;
    *reinterpret_cast<f16x8*>(out + (size_t)r * 512 + c8 * 8) = o;
}

// ---------------------------------------------------------------------------
// z0 extraction: z0[b] = cZfull[b*128 + 0], f32 and f16 copies.
// ---------------------------------------------------------------------------
__global__ __launch_bounds__(256) void k_gather_z0(const float* __restrict__ cZfull,
                                                   float* __restrict__ z0f32,
                                                   f16* __restrict__ z0f16)
{
    const int i = blockIdx.x * 256 + threadIdx.x;     // 512*32 float4s
    if (i >= 512 * 32) return;
    const int b = i >> 5, c4 = i & 31;
    const float4 v = *reinterpret_cast<const float4*>(cZfull + (size_t)b * 16384 + c4 * 4);
    *reinterpret_cast<float4*>(z0f32 + (size_t)b * 128 + c4 * 4) = v;
    f16x4 o;
    o[0] = (f16)v.x; o[1] = (f16)v.y; o[2] = (f16)v.z; o[3] = (f16)v.w;
    *reinterpret_cast<f16x4*>(z0f16 + (size_t)b * 128 + c4 * 4) = o;
}

// ---------------------------------------------------------------------------
// Koopman closed form + linear loss + decin build. 16 threads/row, coalesced.
// ---------------------------------------------------------------------------
__global__ __launch_bounds__(256) void k_koop(const float* __restrict__ cZ,   // [CH][128]
                                              const float* __restrict__ z0,   // [512][128]
                                              const float* __restrict__ pK,   // [512][128]
                                              int g0,
                                              f16* __restrict__ decin,        // [CH][128]
                                              double* __restrict__ p0)
{
    const int idx = blockIdx.x * 256 + threadIdx.x;   // CH*16
    const int r = idx >> 4, c8 = idx & 15;
    const int g = g0 + r;
    const int tt = g & 127;
    const int bb = g >> 7;

    float zt[8];
    *reinterpret_cast<float4*>(zt)     = *reinterpret_cast<const float4*>(cZ + (size_t)r * 128 + c8 * 8);
    *reinterpret_cast<float4*>(zt + 4) = *reinterpret_cast<const float4*>(cZ + (size_t)r * 128 + c8 * 8 + 4);

    double s = 0.0;
    float ov[8];
    if (tt == 0) {
#pragma unroll
        for (int k = 0; k < 8; ++k) ov[k] = zt[k];
    } else {
        float zz[8], qq[8];
        *reinterpret_cast<float4*>(zz)     = *reinterpret_cast<const float4*>(z0 + (size_t)bb * 128 + c8 * 8);
        *reinterpret_cast<float4*>(zz + 4) = *reinterpret_cast<const float4*>(z0 + (size_t)bb * 128 + c8 * 8 + 4);
        *reinterpret_cast<float4*>(qq)     = *reinterpret_cast<const float4*>(pK + (size_t)bb * 128 + c8 * 8);
        *reinterpret_cast<float4*>(qq + 4) = *reinterpret_cast<const float4*>(pK + (size_t)bb * 128 + c8 * 8 + 4);
        const float tf = KDT * (float)tt;
#pragma unroll
        for (int pr = 0; pr < 4; ++pr) {
            const float e = __expf(qq[2 * pr] * tf);
            float sn, cs;
            __sincosf(qq[2 * pr + 1] * tf, &sn, &cs);
            const float zx = zz[2 * pr], zy = zz[2 * pr + 1];
            const float a = e * (cs * zx - sn * zy);
            const float b = e * (sn * zx + cs * zy);
            ov[2 * pr] = a; ov[2 * pr + 1] = b;
            const float d0 = a - zt[2 * pr], d1 = b - zt[2 * pr + 1];
            s += (double)d0 * d0 + (double)d1 * d1;
        }
    }
    f16x8 o;
#pragma unroll
    for (int k = 0; k < 8; ++k) o[k] = (f16)ov[k];
    *reinterpret_cast<f16x8*>(decin + (size_t)r * 128 + c8 * 8) = o;

    __shared__ double sm[256];
    sm[threadIdx.x] = s;
    __syncthreads();
    for (int off = 128; off > 0; off >>= 1) {
        if (threadIdx.x < (unsigned)off) sm[threadIdx.x] += sm[threadIdx.x + off];
        __syncthreads();
    }
    if (threadIdx.x == 0) p0[blockIdx.x] = sm[0];
}

// ---------------------------------------------------------------------------
__global__ __launch_bounds__(256) void k_finalize(const double* __restrict__ pb,
                                                  float* __restrict__ out)
{
    __shared__ double sm[256];
    const int t = threadIdx.x;
    double a0 = 0.0, a1 = 0.0, a2 = 0.0;
    for (int i = t; i < 4096; i += 256) a0 += pb[PB_LIN + i];
    for (int i = t; i < 2048; i += 256) a1 += pb[PB_REC + i];
    for (int i = t; i < 2048; i += 256) a2 += pb[PB_PRED + i];

    double r[3];
    double v[3] = {a0, a1, a2};
    for (int k = 0; k < 3; ++k) {
        sm[t] = v[k];
        __syncthreads();
        for (int o = 128; o > 0; o >>= 1) {
            if (t < o) sm[t] += sm[t + o];
            __syncthreads();
        }
        r[k] = sm[0];
        __syncthreads();
    }
    if (t == 0) {
        const double linear = r[0] / (65024.0 * 128.0);
        const double recon  = r[1] / (512.0 * 512.0);
        const double pred   = r[2] / (65024.0 * 512.0);
        out[0] = (float)(recon + linear + pred);
        out[1] = (float)recon;
        out[2] = (float)linear;
        out[3] = (float)pred;
    }
}

// ---------------------------------------------------------------------------
extern "C" void kernel_launch(void* const* d_in, const int* in_sizes, int n_in,
                              void* d_out, int out_size, void* d_ws, size_t ws_size,
                              hipStream_t stream)
{
    const float* window = (const float*)d_in[0];
    const float* eW1 = (const float*)d_in[1];
    const float* eb1 = (const float*)d_in[2];
    const float* eW2 = (const float*)d_in[3];
    const float* eb2 = (const float*)d_in[4];
    const float* eW3 = (const float*)d_in[5];
    const float* eb3 = (const float*)d_in[6];
    const float* dW1 = (const float*)d_in[7];
    const float* db1 = (const float*)d_in[8];
    const float* dW2 = (const float*)d_in[9];
    const float* db2 = (const float*)d_in[10];
    const float* dW3 = (const float*)d_in[11];
    const float* db3 = (const float*)d_in[12];
    const float* kW1 = (const float*)d_in[13];
    const float* kb1 = (const float*)d_in[14];
    const float* kW2 = (const float*)d_in[15];
    const float* kb2 = (const float*)d_in[16];
    float* out = (float*)d_out;
    (void)in_sizes; (void)n_in; (void)out_size; (void)ws_size;

    char* p = (char*)d_ws;
    size_t off = 0;
    auto takeB = [&](size_t bytes) -> char* {
        char* r = p + off;
        off += (bytes + 255) & ~(size_t)255;
        return r;
    };
    double* pb = (double*)takeB(PB_TOTAL * 8);
    f16* eW1t = (f16*)takeB((size_t)512 * 1024 * 2);
    f16* eW2t = (f16*)takeB((size_t)1024 * 1024 * 2);
    f16* eW3t = (f16*)takeB((size_t)1024 * 128 * 2);
    f16* dW1t = (f16*)takeB((size_t)128 * 1024 * 2);
    f16* dW2t = (f16*)takeB((size_t)1024 * 1024 * 2);
    f16* dW3t = (f16*)takeB((size_t)1024 * 512 * 2);
    f16* kW1t = (f16*)takeB((size_t)128 * 128 * 2);
    f16* kW2t = (f16*)takeB((size_t)128 * 128 * 2);
    float* z0f32 = (float*)takeB((size_t)65536 * 4);
    f16* z0f16 = (f16*)takeB((size_t)65536 * 2);
    f16* hK = (f16*)takeB((size_t)65536 * 2);
    float* pKbuf = (float*)takeB((size_t)65536 * 4);
    float* cZfull = (float*)takeB((size_t)65536 * 128 * 4);   // 32 MB
    f16* cIn = (f16*)takeB((size_t)CH * 512 * 2);             // 16 MB
    f16* cH1 = (f16*)takeB((size_t)CH * 1024 * 2);            // 32 MB
    f16* cH2 = (f16*)takeB((size_t)CH * 1024 * 2);            // 32 MB
    f16* decin = (f16*)takeB((size_t)CH * 128 * 2);           // 4 MB

    hipMemsetAsync(pb, 0, PB_TOTAL * 8, stream);

    auto G = [&](const f16* A, const f16* Wt, const float* b, void* C,
                 int M, int N, int K, bool tanh_, bool f16out) {
        dim3 grid(N / 128, M / 128);
        if (tanh_)       k_gemm_f16<0, true,  true ><<<grid, 256, 0, stream>>>(A, Wt, b, C, M, N, K, nullptr, 0, nullptr, nullptr);
        else if (f16out) k_gemm_f16<0, false, true ><<<grid, 256, 0, stream>>>(A, Wt, b, C, M, N, K, nullptr, 0, nullptr, nullptr);
        else             k_gemm_f16<0, false, false><<<grid, 256, 0, stream>>>(A, Wt, b, C, M, N, K, nullptr, 0, nullptr, nullptr);
    };
    auto WT = [&](const float* W, f16* Wt, int K, int N) {
        k_wt<<<dim3(N / 32, K / 32), 256, 0, stream>>>(W, Wt, K, N);
    };

    // weight prep
    WT(eW1, eW1t, 512, 1024);  WT(eW2, eW2t, 1024, 1024); WT(eW3, eW3t, 1024, 128);
    WT(dW1, dW1t, 128, 1024);  WT(dW2, dW2t, 1024, 1024); WT(dW3, dW3t, 1024, 512);
    WT(kW1, kW1t, 128, 128);   WT(kW2, kW2t, 128, 128);

    // Phase A: encoder over all rows -> cZfull
    for (int c = 0; c < NCHUNK; ++c) {
        const int g0 = c * CH;
        k_gather_all<<<CH * 64 / 256, 256, 0, stream>>>(window, cIn, g0);
        G(cIn, eW1t, eb1, cH1, CH, 1024, 512, true, true);
        G(cH1, eW2t, eb2, cH2, CH, 1024, 1024, true, true);
        G(cH2, eW3t, eb3, cZfull + (size_t)g0 * 128, CH, 128, 1024, false, false);
    }

    // Phase B: z0 + koopman params
    k_gather_z0<<<64, 256, 0, stream>>>(cZfull, z0f32, z0f16);
    G(z0f16, kW1t, kb1, hK, 512, 128, 128, true, true);
    G(hK,    kW2t, kb2, pKbuf, 512, 128, 128, false, false);

    // Phase C: koopman rollout + decoder + losses
    for (int c = 0; c < NCHUNK; ++c) {
        const int g0 = c * CH;
        k_koop<<<CH * 16 / 256, 256, 0, stream>>>(cZfull + (size_t)g0 * 128, z0f32, pKbuf,
                                                  g0, decin, pb + PB_LIN + c * 1024);
        G(decin, dW1t, db1, cH1, CH, 1024, 128, true, true);
        G(cH1,   dW2t, db2, cH2, CH, 1024, 1024, true, true);
        k_gemm_f16<2, false, false><<<dim3(4, CH / 128), 256, 0, stream>>>(
            cH2, dW3t, db3, nullptr, CH, 512, 1024,
            window, g0, pb + PB_REC + c * 512, pb + PB_PRED + c * 512);
    }

    k_finalize<<<1, 256, 0, stream>>>(pb, out);
}